// Round 12
// baseline (265.988 us; speedup 1.0000x reference)
//
#include <hip/hip_runtime.h>
#include <cstddef>
#include <cstdint>

typedef unsigned short ushort_t;
typedef short short8 __attribute__((ext_vector_type(8)));
typedef float f32x4 __attribute__((ext_vector_type(4)));

#define BB 16
#define CC 256
#define CI 128
#define NN 2048
#define BN_EPS 1e-5f

// ---------------- workspace layout (float offsets, all 16B-aligned) -------
#define OFF_LH    0u          // 256x256 bf16 = 32768 fl
#define OFF_RT    32768u      // 256x256 bf16
#define OFF_Q     65536u      // 256 f32
#define OFF_W1    65792u
#define OFF_EG    66048u
#define OFF_BB2   66304u
#define OFF_BFBT  66560u      // 16
#define OFF_BIASP 66576u      // 16x256 f32 = 4096
#define OFF_SS    70672u      // 16x256 f32 = 4096
#define OFF_GH    74768u      // 16x65536 bf16 = 524288 fl
#define OFF_TH    599056u     // 16x65536 bf16
#define OFF_PH    1123344u    // 16x65536 bf16
#define OFF_XH    1647632u    // 16x256x2048 bf16 = 4194304 fl
#define OFF_XHT   5841936u    // 16x2048x256 bf16 = 4194304 fl
#define WS_FLOATS 10036240u   // ~40.1 MB

__device__ __forceinline__ ushort_t f2bf(float f) {
  unsigned int u = __float_as_uint(f);
  u += 0x7fffu + ((u >> 16) & 1u);
  return (ushort_t)(u >> 16);
}
__device__ __forceinline__ float bf2f(ushort_t h) {
  return __uint_as_float((unsigned int)h << 16);
}

__device__ __forceinline__ void gl_lds16(const void* gsrc, void* ldst) {
  __builtin_amdgcn_global_load_lds(
      (const __attribute__((address_space(1))) void*)gsrc,
      (__attribute__((address_space(3))) void*)ldst, 16, 0, 0);
}

// ---------------------------------------------------------------------------
// Proven MFMA core (validated R9/R11, absmax 0.031): C[128x128], 4 waves,
// BK=64, NT-gemm, both-sides ^(row&7) granule swizzle, gload_lds w=16.
// ---------------------------------------------------------------------------
__device__ __forceinline__ void mfma_core(
    const ushort_t* gA, size_t ldA, const ushort_t* gB, size_t ldB,
    int kIters, ushort_t* ldsA, ushort_t* ldsB, f32x4 acc[4][4]) {
  const int t = threadIdx.x;
  const int wave = t >> 6, lane = t & 63;
  const int wm = wave & 1, wn = wave >> 1;
  const int l15 = lane & 15, lhi = lane >> 4;

  for (int kt = 0; kt < kIters; ++kt) {
#pragma unroll
    for (int q = 0; q < 4; ++q) {
      int row = wave * 32 + q * 8 + (lane >> 3);
      int gs = (lane & 7) ^ (row & 7);
      gl_lds16(gA + (size_t)row * ldA + gs * 8, &ldsA[(wave * 4 + q) * 512]);
    }
#pragma unroll
    for (int q = 0; q < 4; ++q) {
      int row = wave * 32 + q * 8 + (lane >> 3);
      int gs = (lane & 7) ^ (row & 7);
      gl_lds16(gB + (size_t)row * ldB + gs * 8, &ldsB[(wave * 4 + q) * 512]);
    }
    __syncthreads();
#pragma unroll
    for (int ks = 0; ks < 2; ++ks) {
      short8 af[4], bf[4];
#pragma unroll
      for (int i = 0; i < 4; ++i) {
        int rowA = wm * 64 + i * 16 + l15;
        int grA = (4 * ks + lhi) ^ (rowA & 7);
        af[i] = *(const short8*)&ldsA[rowA * 64 + grA * 8];
        int rowB = wn * 64 + i * 16 + l15;
        int grB = (4 * ks + lhi) ^ (rowB & 7);
        bf[i] = *(const short8*)&ldsB[rowB * 64 + grB * 8];
      }
#pragma unroll
      for (int i = 0; i < 4; ++i)
#pragma unroll
        for (int j = 0; j < 4; ++j)
          acc[i][j] = __builtin_amdgcn_mfma_f32_16x16x32_bf16(
              af[i], bf[j], acc[i][j], 0, 0, 0);
    }
    __syncthreads();
    gA += 64; gB += 64;
  }
}

#define ACC_INIT(acc) \
  _Pragma("unroll") for (int i_ = 0; i_ < 4; ++i_) \
  _Pragma("unroll") for (int j_ = 0; j_ < 4; ++j_) \
  _Pragma("unroll") for (int e_ = 0; e_ < 4; ++e_) acc[i_][j_][e_] = 0.f;

__device__ __forceinline__ void store_bf16_D(
    f32x4 acc[4][4], ushort_t* D, int ldd, int m0, int n0) {
  int t = threadIdx.x, wave = t >> 6, lane = t & 63;
  int wm = wave & 1, wn = wave >> 1, l15 = lane & 15, lhi = lane >> 4;
#pragma unroll
  for (int i = 0; i < 4; ++i)
#pragma unroll
    for (int j = 0; j < 4; ++j)
#pragma unroll
      for (int r = 0; r < 4; ++r) {
        int a = m0 + wm * 64 + i * 16 + 4 * lhi + r;
        int bc = n0 + wn * 64 + j * 16 + l15;
        D[(size_t)a * ldd + bc] = f2bf(acc[i][j][r]);
      }
}

// ---------------------------------------------------------------------------
// prep (33 blocks): blocks 0-15: L rows (f32 VALU); 16-31: Rt rows; 32: vectors
//   L[o][j]  = (inv[o]/N) * sum_k wout[o][k]*wg[k][j]
//   Rt[a][b] = sum_j wt[j][a]*wp[j][b]
//   q = Wphi^T b_theta; w1 = Wtheta^T b_phi; eg = (inv/N)(wout b_g);
//   bias2 = b_out*inv + beta - mean*inv; bfbt = b_phi.b_theta; s = 0
// ---------------------------------------------------------------------------
__global__ __launch_bounds__(256) void prep(
    const float* __restrict__ wt, const float* __restrict__ wp,
    const float* __restrict__ wg, const float* __restrict__ wout,
    const float* __restrict__ bt, const float* __restrict__ bp,
    const float* __restrict__ bg, const float* __restrict__ gamma,
    const float* __restrict__ beta, const float* __restrict__ run_mean,
    const float* __restrict__ run_var, const float* __restrict__ b_out,
    ushort_t* __restrict__ Lh, ushort_t* __restrict__ Rt,
    float* __restrict__ q, float* __restrict__ w1, float* __restrict__ eg,
    float* __restrict__ bias2, float* __restrict__ bfbt,
    float* __restrict__ s) {
  int blk = blockIdx.x, t = threadIdx.x;
  if (blk < 16) {
    int o = blk * 16 + (t >> 4);
    int j0 = (t & 15) * 16;
    float inv = gamma[o] * rsqrtf(run_var[o] + BN_EPS) * (1.0f / (float)NN);
    float acc[16];
#pragma unroll
    for (int e = 0; e < 16; ++e) acc[e] = 0.f;
    for (int k = 0; k < CI; ++k) {
      float a = wout[(size_t)o * CI + k];
      const float* wgr = &wg[(size_t)k * CC + j0];
#pragma unroll
      for (int e = 0; e < 16; ++e) acc[e] += a * wgr[e];
    }
#pragma unroll
    for (int e = 0; e < 16; ++e)
      Lh[(size_t)o * CC + j0 + e] = f2bf(inv * acc[e]);
  } else if (blk < 32) {
    int a = (blk - 16) * 16 + (t >> 4);
    int b0 = (t & 15) * 16;
    float acc[16];
#pragma unroll
    for (int e = 0; e < 16; ++e) acc[e] = 0.f;
    for (int j = 0; j < CI; ++j) {
      float av = wt[(size_t)j * CC + a];
      const float* wpr = &wp[(size_t)j * CC + b0];
#pragma unroll
      for (int e = 0; e < 16; ++e) acc[e] += av * wpr[e];
    }
#pragma unroll
    for (int e = 0; e < 16; ++e)
      Rt[(size_t)a * CC + b0 + e] = f2bf(acc[e]);
  } else {
    float aq = 0.f, aw = 0.f;
    for (int j = 0; j < CI; ++j) {
      aq += wp[(size_t)j * CC + t] * bt[j];
      aw += wt[(size_t)j * CC + t] * bp[j];
    }
    q[t] = aq; w1[t] = aw;
    float inv = gamma[t] * rsqrtf(run_var[t] + BN_EPS);
    float s2 = 0.f;
    for (int i = 0; i < CI; ++i) s2 += wout[(size_t)t * CI + i] * bg[i];
    eg[t] = inv * (1.0f / (float)NN) * s2;
    bias2[t] = b_out[t] * inv + beta[t] - run_mean[t] * inv;
    if (t == 0) {
      float d = 0.f;
      for (int j = 0; j < CI; ++j) d += bp[j] * bt[j];
      *bfbt = d;
    }
#pragma unroll
    for (int i = 0; i < BB; ++i) s[(size_t)i * CC + t] = 0.f;  // zero s
  }
}

// ---------------------------------------------------------------------------
// cast_x: x f32 -> xhT[b][n][c] + xh[b][c][n] bf16; atomic row-sums -> s
// ---------------------------------------------------------------------------
__global__ __launch_bounds__(256) void cast_x(
    const float* __restrict__ x, ushort_t* __restrict__ xhT,
    ushort_t* __restrict__ xh, float* __restrict__ s) {
  __shared__ float Xs[64][65];
  int n0 = blockIdx.x * 64, c0 = blockIdx.y * 64, b = blockIdx.z;
  int t = threadIdx.x;
  int tr = t >> 4, tc = (t & 15) * 4;
#pragma unroll
  for (int p = 0; p < 4; ++p) {
    int row = p * 16 + tr;
    float4 v = *(const float4*)&x[((size_t)b * CC + c0 + row) * NN + n0 + tc];
    Xs[row][tc] = v.x; Xs[row][tc + 1] = v.y; Xs[row][tc + 2] = v.z; Xs[row][tc + 3] = v.w;
  }
  __syncthreads();
#pragma unroll
  for (int p = 0; p < 4; ++p) {
    int j = p * 16 + tr;
    ushort4 hv;
    hv.x = f2bf(Xs[tc][j]); hv.y = f2bf(Xs[tc + 1][j]);
    hv.z = f2bf(Xs[tc + 2][j]); hv.w = f2bf(Xs[tc + 3][j]);
    *(ushort4*)&xhT[((size_t)b * NN + n0 + j) * CC + c0 + tc] = hv;
  }
  {
    int row = t >> 2, cg = (t & 3) * 16;
    size_t base = ((size_t)b * CC + c0 + row) * NN + n0 + cg;
#pragma unroll
    for (int e = 0; e < 4; ++e) {
      ushort4 hv;
      hv.x = f2bf(Xs[row][cg + 4 * e]);     hv.y = f2bf(Xs[row][cg + 4 * e + 1]);
      hv.z = f2bf(Xs[row][cg + 4 * e + 2]); hv.w = f2bf(Xs[row][cg + 4 * e + 3]);
      *(ushort4*)&xh[base + 4 * e] = hv;
    }
  }
  if (t < 64) {
    float p = 0.f;
    for (int j2 = 0; j2 < 64; ++j2) p += Xs[t][j2];
    atomicAdd(&s[(size_t)b * CC + c0 + t], p);
  }
}

// ---------------------------------------------------------------------------
// k_G: Gh[b] = bf16( xh[b] . xh[b]^T ), single pass K=2048. grid (4 ij, 16 b)
// ---------------------------------------------------------------------------
__global__ __launch_bounds__(256) void k_G(
    const ushort_t* __restrict__ xh, ushort_t* __restrict__ Gh_all) {
  __shared__ __align__(16) ushort_t As[8192], Bs[8192];
  int ij = blockIdx.x, b = blockIdx.y;
  int ti = ij >> 1, tj = ij & 1;
  f32x4 acc[4][4]; ACC_INIT(acc);
  mfma_core(xh + ((size_t)b * CC + ti * 128) * NN, NN,
            xh + ((size_t)b * CC + tj * 128) * NN, NN, NN / 64, As, Bs, acc);
  store_bf16_D(acc, Gh_all + (size_t)b * (CC * CC), CC, ti * 128, tj * 128);
}

// ---------------------------------------------------------------------------
// k_cc (16 blocks, one per batch): v1/v2/sq -> T = L.G -> P = T.R + rank2
//                                  -> bias'. All per-batch, in-block chained.
// ---------------------------------------------------------------------------
__global__ __launch_bounds__(256) void k_cc(
    const float* __restrict__ s, const ushort_t* __restrict__ Lh,
    const ushort_t* __restrict__ Rt, const ushort_t* __restrict__ Gh_all,
    ushort_t* __restrict__ Th_all, ushort_t* __restrict__ Ph_all,
    const float* __restrict__ q, const float* __restrict__ w1,
    const float* __restrict__ eg, const float* __restrict__ bias2,
    const float* __restrict__ bfbt, float* __restrict__ biasp) {
  __shared__ __align__(16) ushort_t As[8192], Bs[8192];
  __shared__ float sl[256], v1l[256], v2l[256], red[256];
  __shared__ float ql[256], egl[256], w1l[256];
  __shared__ float sql;
  int b = blockIdx.x, t = threadIdx.x;
  const ushort_t* Gh = Gh_all + (size_t)b * (CC * CC);
  ushort_t* Th = Th_all + (size_t)b * (CC * CC);
  ushort_t* Ph = Ph_all + (size_t)b * (CC * CC);

  sl[t] = s[(size_t)b * CC + t];
  ql[t] = q[t]; egl[t] = eg[t]; w1l[t] = w1[t];
  __syncthreads();

  {  // v1 = L s, v2 = Rt s (coalesced 16-lane chunks + shfl reduce)
    int rl = t >> 4, ch = t & 15;
    for (int pass = 0; pass < 16; ++pass) {
      int o = pass * 16 + rl;
      float a1 = 0.f, a2 = 0.f;
#pragma unroll
      for (int e = 0; e < 16; ++e) {
        float sv = sl[ch * 16 + e];
        a1 += bf2f(Lh[(size_t)o * CC + ch * 16 + e]) * sv;
        a2 += bf2f(Rt[(size_t)o * CC + ch * 16 + e]) * sv;
      }
#pragma unroll
      for (int w = 8; w >= 1; w >>= 1) {
        a1 += __shfl_xor(a1, w, 16);
        a2 += __shfl_xor(a2, w, 16);
      }
      if (ch == 0) { v1l[o] = a1; v2l[o] = a2; }
    }
    red[t] = sl[t] * ql[t];
  }
  __syncthreads();
  for (int st = 128; st > 0; st >>= 1) {
    if (t < st) red[t] += red[t + st];
    __syncthreads();
  }
  if (t == 0) sql = red[0];
  __syncthreads();

  // T = L . G  (4 tiles, sequential)
  for (int m0 = 0; m0 < CC; m0 += 128)
    for (int n0 = 0; n0 < CC; n0 += 128) {
      f32x4 acc[4][4]; ACC_INIT(acc);
      mfma_core(Lh + (size_t)m0 * CC, CC, Gh + (size_t)n0 * CC, CC, 4, As, Bs, acc);
      store_bf16_D(acc, Th, CC, m0, n0);
    }
  __syncthreads();  // vmcnt drained -> Th visible to this block via L2

  // P = T . R + rank-2 terms
  int wave = t >> 6, lane = t & 63;
  int wm = wave & 1, wn = wave >> 1, l15 = lane & 15, lhi = lane >> 4;
  for (int m0 = 0; m0 < CC; m0 += 128)
    for (int n0 = 0; n0 < CC; n0 += 128) {
      f32x4 acc[4][4]; ACC_INIT(acc);
      mfma_core(Th + (size_t)m0 * CC, CC, Rt + (size_t)n0 * CC, CC, 4, As, Bs, acc);
#pragma unroll
      for (int i = 0; i < 4; ++i)
#pragma unroll
        for (int r = 0; r < 4; ++r) {
          int o = m0 + wm * 64 + i * 16 + 4 * lhi + r;
          float vo = v1l[o] + (float)NN * egl[o];
          float eo = egl[o];
#pragma unroll
          for (int j = 0; j < 4; ++j) {
            int c = n0 + wn * 64 + j * 16 + l15;
            Ph[(size_t)o * CC + c] = f2bf(acc[i][j][r] + eo * v2l[c] + vo * w1l[c]);
          }
        }
    }
  __syncthreads();

  {  // bias'[o] = T[o,:].q + eg*sq + (v1+N*eg)*bfbt + bias2
    float bf = *bfbt;
    int rl = t >> 4, ch = t & 15;
    for (int pass = 0; pass < 16; ++pass) {
      int o = pass * 16 + rl;
      float a = 0.f;
#pragma unroll
      for (int e = 0; e < 16; ++e)
        a += bf2f(Th[(size_t)o * CC + ch * 16 + e]) * ql[ch * 16 + e];
#pragma unroll
      for (int w = 8; w >= 1; w >>= 1) a += __shfl_xor(a, w, 16);
      if (ch == 0)
        biasp[(size_t)b * CC + o] = a + egl[o] * sql +
            (v1l[o] + (float)NN * egl[o]) * bf + bias2[o];
    }
  }
}

// ---------------------------------------------------------------------------
// k_out: out = P . x + bias' + x   (residual from xh bf16). grid (16,2,16)
// ---------------------------------------------------------------------------
__global__ __launch_bounds__(256) void k_out(
    const ushort_t* __restrict__ Ph_all, const ushort_t* __restrict__ xhT,
    const ushort_t* __restrict__ xh, const float* __restrict__ biasp,
    float* __restrict__ out) {
  __shared__ __align__(16) ushort_t As[8192], Bs[8192];
  int n0 = blockIdx.x * 128, o0 = blockIdx.y * 128, b = blockIdx.z;
  f32x4 acc[4][4]; ACC_INIT(acc);
  mfma_core(Ph_all + (size_t)b * (CC * CC) + (size_t)o0 * CC, CC,
            xhT + ((size_t)b * NN + n0) * CC, CC, 4, As, Bs, acc);
  int t = threadIdx.x, wave = t >> 6, lane = t & 63;
  int wm = wave & 1, wn = wave >> 1, l15 = lane & 15, lhi = lane >> 4;
#pragma unroll
  for (int i = 0; i < 4; ++i)
#pragma unroll
    for (int r = 0; r < 4; ++r) {
      int o = o0 + wm * 64 + i * 16 + 4 * lhi + r;
      float bo = biasp[(size_t)b * CC + o];
#pragma unroll
      for (int j = 0; j < 4; ++j) {
        int n = n0 + wn * 64 + j * 16 + l15;
        size_t idx = ((size_t)b * CC + o) * NN + n;
        out[idx] = acc[i][j][r] + bo + bf2f(xh[idx]);
      }
    }
}

// ---------------------------------------------------------------------------
extern "C" void kernel_launch(void* const* d_in, const int* in_sizes, int n_in,
                              void* d_out, int out_size, void* d_ws, size_t ws_size,
                              hipStream_t stream) {
  const float* x        = (const float*)d_in[0];
  const float* w_theta  = (const float*)d_in[1];
  const float* b_theta  = (const float*)d_in[2];
  const float* w_phi    = (const float*)d_in[3];
  const float* b_phi    = (const float*)d_in[4];
  const float* w_g      = (const float*)d_in[5];
  const float* b_g      = (const float*)d_in[6];
  const float* w_out    = (const float*)d_in[7];
  const float* b_out    = (const float*)d_in[8];
  const float* gamma    = (const float*)d_in[9];
  const float* beta     = (const float*)d_in[10];
  const float* run_mean = (const float*)d_in[11];
  const float* run_var  = (const float*)d_in[12];
  float* out = (float*)d_out;
  float* ws  = (float*)d_ws;

  if (ws_size < (size_t)WS_FLOATS * sizeof(float)) return;

  ushort_t* Lh    = (ushort_t*)(ws + OFF_LH);
  ushort_t* Rt    = (ushort_t*)(ws + OFF_RT);
  float*    q     = ws + OFF_Q;
  float*    w1    = ws + OFF_W1;
  float*    eg    = ws + OFF_EG;
  float*    bias2 = ws + OFF_BB2;
  float*    bfbt  = ws + OFF_BFBT;
  float*    biasp = ws + OFF_BIASP;
  float*    s     = ws + OFF_SS;
  ushort_t* Gh    = (ushort_t*)(ws + OFF_GH);
  ushort_t* Th    = (ushort_t*)(ws + OFF_TH);
  ushort_t* Ph    = (ushort_t*)(ws + OFF_PH);
  ushort_t* xh    = (ushort_t*)(ws + OFF_XH);
  ushort_t* xhT   = (ushort_t*)(ws + OFF_XHT);

  prep<<<dim3(33), 256, 0, stream>>>(w_theta, w_phi, w_g, w_out,
      b_theta, b_phi, b_g, gamma, beta, run_mean, run_var, b_out,
      Lh, Rt, q, w1, eg, bias2, bfbt, s);
  cast_x<<<dim3(NN / 64, CC / 64, BB), 256, 0, stream>>>(x, xhT, xh, s);
  k_G<<<dim3(4, BB), 256, 0, stream>>>(xh, Gh);
  k_cc<<<dim3(BB), 256, 0, stream>>>(s, Lh, Rt, Gh, Th, Ph,
                                     q, w1, eg, bias2, bfbt, biasp);
  k_out<<<dim3(NN / 128, CC / 128, BB), 256, 0, stream>>>(Ph, xhT, xh, biasp, out);
}